// Round 6
// baseline (181.341 us; speedup 1.0000x reference)
//
#include <hip/hip_runtime.h>
#include <hip/hip_bf16.h>
#include <math.h>

#define B 4
#define L 1024
#define D 256
#define H 8
#define HD 64

// workspace layout (float offsets)
#define KB_OFF  (H*B*L*HD/2)           // Q bf16 occupies [0, KB_OFF) floats
#define VR_OFF  (H*B*L*HD)             // K bf16 occupies [KB_OFF, VR_OFF)
#define T_OFF   (VR_OFF + H*B*L)       // diagonal sums (zeroed each launch)
#define GS_OFF  (T_OFF + H*B*L)        // softmax denominators (zeroed each launch)
// total floats: GS_OFF + H*B*L = 2195456 (~8.8 MB)

typedef short short8 __attribute__((ext_vector_type(8)));
typedef float f32x16 __attribute__((ext_vector_type(16)));

// ---------------------------------------------------------------------------
// Kernel 1: xpe = x+pe;  Q = bf16(xpe@Wq + bq)  -> [hb][l][64] row-major
//           K = bf16(xpe@Wk + bk)               -> [hb][l][64] row-major
//           lvr[hb][k] = log2(sigmoid(x@Wv))[h,b,L-1-k] (fp32)
// ---------------------------------------------------------------------------
__global__ __launch_bounds__(256) void qkv_kernel(
    const float* __restrict__ x, const float* __restrict__ Wq,
    const float* __restrict__ bq, const float* __restrict__ Wk,
    const float* __restrict__ bk, const float* __restrict__ Wv,
    const float* __restrict__ pe, float* __restrict__ ws)
{
  __shared__ float xs[8][D];
  __shared__ float xp[8][D];
  const int tid = threadIdx.x;
  const int r0 = blockIdx.x * 8;

  for (int idx = tid; idx < 8 * D; idx += 256) {
    int rr = idx >> 8, c = idx & 255;
    int gr = r0 + rr;
    int l = gr & 1023;
    float xv = x[gr * D + c];
    xs[rr][c] = xv;
    xp[rr][c] = xv + pe[l * D + c];
  }
  __syncthreads();

  if (tid < 64) {
    int rr = tid >> 3, h = tid & 7;
    float acc = 0.f;
    for (int d = 0; d < D; ++d) acc += xs[rr][d] * Wv[d * H + h];
    float v = 1.f / (1.f + __expf(-acc));
    int gr = r0 + rr;
    int b = gr >> 10, l = gr & 1023;
    ws[VR_OFF + (h * B + b) * L + (L - 1 - l)] = __log2f(v);
  }

  float accq0[8], accq1[8], acck0[8], acck1[8];
#pragma unroll
  for (int r = 0; r < 8; ++r) { accq0[r] = 0.f; accq1[r] = 0.f; acck0[r] = 0.f; acck1[r] = 0.f; }

  const int c0 = tid, c1 = tid + 256;
  for (int d = 0; d < D; ++d) {
    float wq0 = Wq[d * 512 + c0], wq1 = Wq[d * 512 + c1];
    float wk0 = Wk[d * 512 + c0], wk1 = Wk[d * 512 + c1];
#pragma unroll
    for (int r = 0; r < 8; ++r) {
      float xv = xp[r][d];
      accq0[r] += xv * wq0; accq1[r] += xv * wq1;
      acck0[r] += xv * wk0; acck1[r] += xv * wk1;
    }
  }

  __hip_bfloat16* Qb = (__hip_bfloat16*)ws;
  __hip_bfloat16* Kb = (__hip_bfloat16*)(ws + KB_OFF);
  {
    int h = c0 >> 6, hd = c0 & 63;
    float bqv = bq[c0], bkv = bk[c0];
#pragma unroll
    for (int r = 0; r < 8; ++r) {
      int gr = r0 + r;
      int b = gr >> 10, l = gr & 1023;
      int hb = h * B + b;
      Qb[(((hb << 10) + l) << 6) + hd] = __float2bfloat16(accq0[r] + bqv);
      Kb[(((hb << 10) + l) << 6) + hd] = __float2bfloat16(acck0[r] + bkv);
    }
  }
  {
    int h = c1 >> 6, hd = c1 & 63;
    float bqv = bq[c1], bkv = bk[c1];
#pragma unroll
    for (int r = 0; r < 8; ++r) {
      int gr = r0 + r;
      int b = gr >> 10, l = gr & 1023;
      int hb = h * B + b;
      Qb[(((hb << 10) + l) << 6) + hd] = __float2bfloat16(accq1[r] + bqv);
      Kb[(((hb << 10) + l) << 6) + hd] = __float2bfloat16(acck1[r] + bkv);
    }
  }
}

// ---------------------------------------------------------------------------
// Kernel 2a: gs[hb][q] += sum over half the k range of exp(S(q,k)/8).
// Grid 2048 = (khalf 2) x (qt 32) x (hb 32); hb = i&31 -> XCD-pinned.
// Wave w: kt = khalf*16 + {w, w+4, w+8, w+12}, two independent MFMA chains.
// No max subtraction (|S/8| small, fp32-safe — validated rounds 3-4).
// ---------------------------------------------------------------------------
__global__ __launch_bounds__(256) void gsum_kernel(float* __restrict__ ws)
{
  __shared__ float smerge[4][32];
  const int tid = threadIdx.x;
  const int w = tid >> 6, lane = tid & 63;
  const int i = blockIdx.x;
  const int hb = i & 31;
  const int qt = (i >> 5) & 31;
  const int khalf = i >> 10;

  const __hip_bfloat16* Qb = (const __hip_bfloat16*)ws + ((size_t)hb << 16);
  const __hip_bfloat16* Kb = (const __hip_bfloat16*)(ws + KB_OFF) + ((size_t)hb << 16);

  const int q0 = qt << 5;
  const int qrow = q0 + (lane & 31);
  const int dlo = (lane >> 5) << 3;

  const __hip_bfloat16* qr = Qb + (qrow << 6) + dlo;
  short8 qf0 = *(const short8*)(qr);
  short8 qf1 = *(const short8*)(qr + 16);
  short8 qf2 = *(const short8*)(qr + 32);
  short8 qf3 = *(const short8*)(qr + 48);

  float s_part = 0.f;
#pragma unroll
  for (int t = 0; t < 2; ++t) {
    const int kta = (khalf << 4) + (t << 3) + w;
    const int ktb = kta + 4;
    const __hip_bfloat16* kra = Kb + (((kta << 5) + (lane & 31)) << 6) + dlo;
    const __hip_bfloat16* krb = Kb + (((ktb << 5) + (lane & 31)) << 6) + dlo;
    short8 ka0 = *(const short8*)(kra);
    short8 ka1 = *(const short8*)(kra + 16);
    short8 ka2 = *(const short8*)(kra + 32);
    short8 ka3 = *(const short8*)(kra + 48);
    short8 kb0 = *(const short8*)(krb);
    short8 kb1 = *(const short8*)(krb + 16);
    short8 kb2 = *(const short8*)(krb + 32);
    short8 kb3 = *(const short8*)(krb + 48);
    f32x16 acca = {0.f,0.f,0.f,0.f,0.f,0.f,0.f,0.f,0.f,0.f,0.f,0.f,0.f,0.f,0.f,0.f};
    f32x16 accb = {0.f,0.f,0.f,0.f,0.f,0.f,0.f,0.f,0.f,0.f,0.f,0.f,0.f,0.f,0.f,0.f};
    acca = __builtin_amdgcn_mfma_f32_32x32x16_bf16(ka0, qf0, acca, 0, 0, 0);
    accb = __builtin_amdgcn_mfma_f32_32x32x16_bf16(kb0, qf0, accb, 0, 0, 0);
    acca = __builtin_amdgcn_mfma_f32_32x32x16_bf16(ka1, qf1, acca, 0, 0, 0);
    accb = __builtin_amdgcn_mfma_f32_32x32x16_bf16(kb1, qf1, accb, 0, 0, 0);
    acca = __builtin_amdgcn_mfma_f32_32x32x16_bf16(ka2, qf2, acca, 0, 0, 0);
    accb = __builtin_amdgcn_mfma_f32_32x32x16_bf16(kb2, qf2, accb, 0, 0, 0);
    acca = __builtin_amdgcn_mfma_f32_32x32x16_bf16(ka3, qf3, acca, 0, 0, 0);
    accb = __builtin_amdgcn_mfma_f32_32x32x16_bf16(kb3, qf3, accb, 0, 0, 0);
#pragma unroll
    for (int r = 0; r < 16; ++r) s_part += __expf(acca[r] * 0.125f);
#pragma unroll
    for (int r = 0; r < 16; ++r) s_part += __expf(accb[r] * 0.125f);
  }
  s_part += __shfl_xor(s_part, 32);
  if (lane < 32) smerge[w][lane] = s_part;
  __syncthreads();
  if (tid < 32) {
    float s = smerge[0][tid] + smerge[1][tid] + smerge[2][tid] + smerge[3][tid];
    atomicAdd(&ws[GS_OFF + (hb << 10) + q0 + tid], s);
  }
}

// ---------------------------------------------------------------------------
// Kernel 2b: diagonal sweep. Wave owns (dt = kt-qt, chunk of <=4 qt).
// Per lane the 16 output slots j = dt*32 + coff + off(r) - (lane&31) are
// CONSTANT over the sweep -> accumulate in registers, no atomics in loop.
// p = 2^(S*0.125*log2e + log2(vr[k]) - log2(gs[q])).  Flush once, masked j>=0.
// Grid 1152 = (cgroup 36) x (hb 32); hb = i&31 -> XCD-pinned.
// ---------------------------------------------------------------------------
__global__ __launch_bounds__(256) void diag_kernel(float* __restrict__ ws)
{
  const int tid = threadIdx.x;
  const int w = tid >> 6, lane = tid & 63;
  const int i = blockIdx.x;
  const int hb = i & 31;
  const int cg = i >> 5;            // 0..35
  const int chunk = cg * 4 + w;     // 0..143

  // decode chunk -> (dt, qc): chunks per diagonal = ceil((32-dt)/4)
  int dt = 0, cum = 0;
  for (;;) {
    int n = (32 - dt + 3) >> 2;
    if (chunk < cum + n) break;
    cum += n; ++dt;
  }
  const int qt0 = (chunk - cum) << 2;
  const int qtmax = 31 - dt;

  const __hip_bfloat16* Qb = (const __hip_bfloat16*)ws + ((size_t)hb << 16);
  const __hip_bfloat16* Kb = (const __hip_bfloat16*)(ws + KB_OFF) + ((size_t)hb << 16);
  const float* __restrict__ gs = ws + GS_OFF + (hb << 10);
  const float* __restrict__ lvr = ws + VR_OFF + (hb << 10);

  const int dlo = (lane >> 5) << 3;
  const int coff = (lane >> 5) << 2;

  float accT[16];
#pragma unroll
  for (int r = 0; r < 16; ++r) accT[r] = 0.f;

#pragma unroll 2
  for (int u = 0; u < 4; ++u) {
    const int qt = qt0 + u;
    if (qt > qtmax) break;
    const int kt = qt + dt;
    const int qrow = (qt << 5) + (lane & 31);
    const __hip_bfloat16* qr = Qb + (qrow << 6) + dlo;
    const __hip_bfloat16* kr = Kb + (((kt << 5) + (lane & 31)) << 6) + dlo;
    short8 qf0 = *(const short8*)(qr);
    short8 qf1 = *(const short8*)(qr + 16);
    short8 qf2 = *(const short8*)(qr + 32);
    short8 qf3 = *(const short8*)(qr + 48);
    short8 kf0 = *(const short8*)(kr);
    short8 kf1 = *(const short8*)(kr + 16);
    short8 kf2 = *(const short8*)(kr + 32);
    short8 kf3 = *(const short8*)(kr + 48);
    // lvr for this lane's 16 k slots: 4x float4 at (kt*32 + coff) + {0,8,16,24}
    const float* lb = lvr + (kt << 5) + coff;
    float4 lv0 = *(const float4*)(lb);
    float4 lv1 = *(const float4*)(lb + 8);
    float4 lv2 = *(const float4*)(lb + 16);
    float4 lv3 = *(const float4*)(lb + 24);
    float l2g = __log2f(gs[qrow]);

    f32x16 acc = {0.f,0.f,0.f,0.f,0.f,0.f,0.f,0.f,0.f,0.f,0.f,0.f,0.f,0.f,0.f,0.f};
    acc = __builtin_amdgcn_mfma_f32_32x32x16_bf16(kf0, qf0, acc, 0, 0, 0);
    acc = __builtin_amdgcn_mfma_f32_32x32x16_bf16(kf1, qf1, acc, 0, 0, 0);
    acc = __builtin_amdgcn_mfma_f32_32x32x16_bf16(kf2, qf2, acc, 0, 0, 0);
    acc = __builtin_amdgcn_mfma_f32_32x32x16_bf16(kf3, qf3, acc, 0, 0, 0);

    const float c = 0.125f * 1.44269504f;
#pragma unroll
    for (int r = 0; r < 4; ++r) accT[r]      += exp2f(acc[r]      * c + (&lv0.x)[r] - l2g);
#pragma unroll
    for (int r = 0; r < 4; ++r) accT[r + 4]  += exp2f(acc[r + 4]  * c + (&lv1.x)[r] - l2g);
#pragma unroll
    for (int r = 0; r < 4; ++r) accT[r + 8]  += exp2f(acc[r + 8]  * c + (&lv2.x)[r] - l2g);
#pragma unroll
    for (int r = 0; r < 4; ++r) accT[r + 12] += exp2f(acc[r + 12] * c + (&lv3.x)[r] - l2g);
  }

  // single flush: j is constant per (lane, r) for this diagonal
  float* Th = ws + T_OFF + (hb << 10);
#pragma unroll
  for (int r = 0; r < 16; ++r) {
    int j = (dt << 5) + coff + (r & 3) + ((r >> 2) << 3) - (lane & 31);
    if (j >= 0) atomicAdd(&Th[j], accT[r]);
  }
}

// ---------------------------------------------------------------------------
// Kernel 3: out[b,j,h] = (T[j-1]+T[j]+T[j+1]) / cnt[j]
// ---------------------------------------------------------------------------
__global__ __launch_bounds__(256) void out_kernel(const float* __restrict__ ws,
                                                  float* __restrict__ out)
{
  int o = blockIdx.x * 256 + threadIdx.x;
  if (o >= B * L * H) return;
  int h = o & 7;
  int j = (o >> 3) & 1023;
  int b = o >> 13;
  const float* T = ws + T_OFF + ((h * B + b) << 10);
  float s = T[j];
  float cnt = 3.f;
  if (j > 0) s += T[j - 1];
  if (j < 1023) s += T[j + 1];
  if (j == 0 || j == 1023) cnt = 2.f;
  out[o] = s / cnt;
}

extern "C" void kernel_launch(void* const* d_in, const int* in_sizes, int n_in,
                              void* d_out, int out_size, void* d_ws, size_t ws_size,
                              hipStream_t stream)
{
  const float* x  = (const float*)d_in[0];
  const float* Wq = (const float*)d_in[1];
  const float* bq = (const float*)d_in[2];
  const float* Wk = (const float*)d_in[3];
  const float* bk = (const float*)d_in[4];
  const float* Wv = (const float*)d_in[5];
  const float* pe = (const float*)d_in[6];
  float* ws = (float*)d_ws;
  float* out = (float*)d_out;

  // zero T and gs (adjacent regions) every launch
  (void)hipMemsetAsync(ws + T_OFF, 0, 2 * H * B * L * sizeof(float), stream);
  qkv_kernel<<<dim3((B * L) / 8), dim3(256), 0, stream>>>(x, Wq, bq, Wk, bk, Wv, pe, ws);
  gsum_kernel<<<dim3(2048), dim3(256), 0, stream>>>(ws);
  diag_kernel<<<dim3(1152), dim3(256), 0, stream>>>(ws);
  out_kernel<<<dim3((B * L * H + 255) / 256), dim3(256), 0, stream>>>(ws, out);
}

// Round 7
// 113.441 us; speedup vs baseline: 1.5985x; 1.5985x over previous
//
#include <hip/hip_runtime.h>
#include <hip/hip_bf16.h>
#include <math.h>

#define B 4
#define L 1024
#define D 256
#define H 8
#define HD 64

// workspace layout (float offsets)
#define KB_OFF  (H*B*L*HD/2)           // Q bf16 occupies [0, KB_OFF) floats
#define VR_OFF  (H*B*L*HD)             // K bf16 occupies [KB_OFF, VR_OFF)
#define T_OFF   (VR_OFF + H*B*L)       // diagonal sums (zeroed each launch)
#define GS_OFF  (T_OFF + H*B*L)        // softmax denominators (zeroed each launch)
// total floats: GS_OFF + H*B*L = 2195456 (~8.8 MB)

typedef short short8 __attribute__((ext_vector_type(8)));
typedef float f32x16 __attribute__((ext_vector_type(16)));

// ---------------------------------------------------------------------------
// Kernel 1: xpe = x+pe;  Q = bf16(xpe@Wq + bq)  -> [hb][l][64] row-major
//           K = bf16(xpe@Wk + bk)               -> [hb][l][64] row-major
//           lvr[hb][k] = log2(sigmoid(x@Wv))[h,b,L-1-k] (fp32)
// ---------------------------------------------------------------------------
__global__ __launch_bounds__(256) void qkv_kernel(
    const float* __restrict__ x, const float* __restrict__ Wq,
    const float* __restrict__ bq, const float* __restrict__ Wk,
    const float* __restrict__ bk, const float* __restrict__ Wv,
    const float* __restrict__ pe, float* __restrict__ ws)
{
  __shared__ float xs[8][D];
  __shared__ float xp[8][D];
  const int tid = threadIdx.x;
  const int r0 = blockIdx.x * 8;

  for (int idx = tid; idx < 8 * D; idx += 256) {
    int rr = idx >> 8, c = idx & 255;
    int gr = r0 + rr;
    int l = gr & 1023;
    float xv = x[gr * D + c];
    xs[rr][c] = xv;
    xp[rr][c] = xv + pe[l * D + c];
  }
  __syncthreads();

  if (tid < 64) {
    int rr = tid >> 3, h = tid & 7;
    float acc = 0.f;
    for (int d = 0; d < D; ++d) acc += xs[rr][d] * Wv[d * H + h];
    float v = 1.f / (1.f + __expf(-acc));
    int gr = r0 + rr;
    int b = gr >> 10, l = gr & 1023;
    ws[VR_OFF + (h * B + b) * L + (L - 1 - l)] = __log2f(v);
  }

  float accq0[8], accq1[8], acck0[8], acck1[8];
#pragma unroll
  for (int r = 0; r < 8; ++r) { accq0[r] = 0.f; accq1[r] = 0.f; acck0[r] = 0.f; acck1[r] = 0.f; }

  const int c0 = tid, c1 = tid + 256;
  for (int d = 0; d < D; ++d) {
    float wq0 = Wq[d * 512 + c0], wq1 = Wq[d * 512 + c1];
    float wk0 = Wk[d * 512 + c0], wk1 = Wk[d * 512 + c1];
#pragma unroll
    for (int r = 0; r < 8; ++r) {
      float xv = xp[r][d];
      accq0[r] += xv * wq0; accq1[r] += xv * wq1;
      acck0[r] += xv * wk0; acck1[r] += xv * wk1;
    }
  }

  __hip_bfloat16* Qb = (__hip_bfloat16*)ws;
  __hip_bfloat16* Kb = (__hip_bfloat16*)(ws + KB_OFF);
  {
    int h = c0 >> 6, hd = c0 & 63;
    float bqv = bq[c0], bkv = bk[c0];
#pragma unroll
    for (int r = 0; r < 8; ++r) {
      int gr = r0 + r;
      int b = gr >> 10, l = gr & 1023;
      int hb = h * B + b;
      Qb[(((hb << 10) + l) << 6) + hd] = __float2bfloat16(accq0[r] + bqv);
      Kb[(((hb << 10) + l) << 6) + hd] = __float2bfloat16(acck0[r] + bkv);
    }
  }
  {
    int h = c1 >> 6, hd = c1 & 63;
    float bqv = bq[c1], bkv = bk[c1];
#pragma unroll
    for (int r = 0; r < 8; ++r) {
      int gr = r0 + r;
      int b = gr >> 10, l = gr & 1023;
      int hb = h * B + b;
      Qb[(((hb << 10) + l) << 6) + hd] = __float2bfloat16(accq1[r] + bqv);
      Kb[(((hb << 10) + l) << 6) + hd] = __float2bfloat16(acck1[r] + bkv);
    }
  }
}

// ---------------------------------------------------------------------------
// Kernel 2a: gs[hb][q] += sum over half the k range of exp(S(q,k)/8).
// Grid 2048 = (khalf 2) x (qt 32) x (hb 32); hb = i&31 -> XCD-pinned.
// ---------------------------------------------------------------------------
__global__ __launch_bounds__(256) void gsum_kernel(float* __restrict__ ws)
{
  __shared__ float smerge[4][32];
  const int tid = threadIdx.x;
  const int w = tid >> 6, lane = tid & 63;
  const int i = blockIdx.x;
  const int hb = i & 31;
  const int qt = (i >> 5) & 31;
  const int khalf = i >> 10;

  const __hip_bfloat16* Qb = (const __hip_bfloat16*)ws + ((size_t)hb << 16);
  const __hip_bfloat16* Kb = (const __hip_bfloat16*)(ws + KB_OFF) + ((size_t)hb << 16);

  const int q0 = qt << 5;
  const int qrow = q0 + (lane & 31);
  const int dlo = (lane >> 5) << 3;

  const __hip_bfloat16* qr = Qb + (qrow << 6) + dlo;
  short8 qf0 = *(const short8*)(qr);
  short8 qf1 = *(const short8*)(qr + 16);
  short8 qf2 = *(const short8*)(qr + 32);
  short8 qf3 = *(const short8*)(qr + 48);

  float s_part = 0.f;
#pragma unroll
  for (int t = 0; t < 2; ++t) {
    const int kta = (khalf << 4) + (t << 3) + w;
    const int ktb = kta + 4;
    const __hip_bfloat16* kra = Kb + (((kta << 5) + (lane & 31)) << 6) + dlo;
    const __hip_bfloat16* krb = Kb + (((ktb << 5) + (lane & 31)) << 6) + dlo;
    short8 ka0 = *(const short8*)(kra);
    short8 ka1 = *(const short8*)(kra + 16);
    short8 ka2 = *(const short8*)(kra + 32);
    short8 ka3 = *(const short8*)(kra + 48);
    short8 kb0 = *(const short8*)(krb);
    short8 kb1 = *(const short8*)(krb + 16);
    short8 kb2 = *(const short8*)(krb + 32);
    short8 kb3 = *(const short8*)(krb + 48);
    f32x16 acca = {0.f,0.f,0.f,0.f,0.f,0.f,0.f,0.f,0.f,0.f,0.f,0.f,0.f,0.f,0.f,0.f};
    f32x16 accb = {0.f,0.f,0.f,0.f,0.f,0.f,0.f,0.f,0.f,0.f,0.f,0.f,0.f,0.f,0.f,0.f};
    acca = __builtin_amdgcn_mfma_f32_32x32x16_bf16(ka0, qf0, acca, 0, 0, 0);
    accb = __builtin_amdgcn_mfma_f32_32x32x16_bf16(kb0, qf0, accb, 0, 0, 0);
    acca = __builtin_amdgcn_mfma_f32_32x32x16_bf16(ka1, qf1, acca, 0, 0, 0);
    accb = __builtin_amdgcn_mfma_f32_32x32x16_bf16(kb1, qf1, accb, 0, 0, 0);
    acca = __builtin_amdgcn_mfma_f32_32x32x16_bf16(ka2, qf2, acca, 0, 0, 0);
    accb = __builtin_amdgcn_mfma_f32_32x32x16_bf16(kb2, qf2, accb, 0, 0, 0);
    acca = __builtin_amdgcn_mfma_f32_32x32x16_bf16(ka3, qf3, acca, 0, 0, 0);
    accb = __builtin_amdgcn_mfma_f32_32x32x16_bf16(kb3, qf3, accb, 0, 0, 0);
#pragma unroll
    for (int r = 0; r < 16; ++r) s_part += __expf(acca[r] * 0.125f);
#pragma unroll
    for (int r = 0; r < 16; ++r) s_part += __expf(accb[r] * 0.125f);
  }
  s_part += __shfl_xor(s_part, 32);
  if (lane < 32) smerge[w][lane] = s_part;
  __syncthreads();
  if (tid < 32) {
    float s = smerge[0][tid] + smerge[1][tid] + smerge[2][tid] + smerge[3][tid];
    atomicAdd(&ws[GS_OFF + (hb << 10) + q0 + tid], s);
  }
}

// ---------------------------------------------------------------------------
// Kernel 2b: diagonal sweep. Wave owns (dt = kt-qt, chunk of <=4 qt).
// Register accumulation over the sweep (j constant per (lane,r)), then:
//   wave flush -> per-wave LDS segment via ds_add (16 LDS atomics/lane)
//   block flush -> ONE global atomicAdd per thread (256/block, was 4096).
// Grid 1152 = (cgroup 36) x (hb 32); hb = i&31 -> XCD-pinned.
// ---------------------------------------------------------------------------
__global__ __launch_bounds__(256) void diag_kernel(float* __restrict__ ws)
{
  __shared__ float Tst[4][64];      // per-wave diagonal segment, idx = j - (dt*32-31)
  __shared__ int jbs[4];
  const int tid = threadIdx.x;
  const int w = tid >> 6, lane = tid & 63;
  const int i = blockIdx.x;
  const int hb = i & 31;
  const int cg = i >> 5;            // 0..35
  const int chunk = cg * 4 + w;     // 0..143

  // decode chunk -> (dt, qc): chunks per diagonal = ceil((32-dt)/4)
  int dt = 0, cum = 0;
  for (;;) {
    int n = (32 - dt + 3) >> 2;
    if (chunk < cum + n) break;
    cum += n; ++dt;
  }
  const int qt0 = (chunk - cum) << 2;
  const int qtmax = 31 - dt;

  (&Tst[0][0])[tid] = 0.f;
  if (lane == 0) jbs[w] = (dt << 5) - 31;
  __syncthreads();

  const __hip_bfloat16* Qb = (const __hip_bfloat16*)ws + ((size_t)hb << 16);
  const __hip_bfloat16* Kb = (const __hip_bfloat16*)(ws + KB_OFF) + ((size_t)hb << 16);
  const float* __restrict__ gs = ws + GS_OFF + (hb << 10);
  const float* __restrict__ lvr = ws + VR_OFF + (hb << 10);

  const int dlo = (lane >> 5) << 3;
  const int coff = (lane >> 5) << 2;

  float accT[16];
#pragma unroll
  for (int r = 0; r < 16; ++r) accT[r] = 0.f;

#pragma unroll 2
  for (int u = 0; u < 4; ++u) {
    const int qt = qt0 + u;
    if (qt > qtmax) break;
    const int kt = qt + dt;
    const int qrow = (qt << 5) + (lane & 31);
    const __hip_bfloat16* qr = Qb + (qrow << 6) + dlo;
    const __hip_bfloat16* kr = Kb + (((kt << 5) + (lane & 31)) << 6) + dlo;
    short8 qf0 = *(const short8*)(qr);
    short8 qf1 = *(const short8*)(qr + 16);
    short8 qf2 = *(const short8*)(qr + 32);
    short8 qf3 = *(const short8*)(qr + 48);
    short8 kf0 = *(const short8*)(kr);
    short8 kf1 = *(const short8*)(kr + 16);
    short8 kf2 = *(const short8*)(kr + 32);
    short8 kf3 = *(const short8*)(kr + 48);
    const float* lb = lvr + (kt << 5) + coff;
    float4 lv0 = *(const float4*)(lb);
    float4 lv1 = *(const float4*)(lb + 8);
    float4 lv2 = *(const float4*)(lb + 16);
    float4 lv3 = *(const float4*)(lb + 24);
    float l2g = __log2f(gs[qrow]);

    f32x16 acc = {0.f,0.f,0.f,0.f,0.f,0.f,0.f,0.f,0.f,0.f,0.f,0.f,0.f,0.f,0.f,0.f};
    acc = __builtin_amdgcn_mfma_f32_32x32x16_bf16(kf0, qf0, acc, 0, 0, 0);
    acc = __builtin_amdgcn_mfma_f32_32x32x16_bf16(kf1, qf1, acc, 0, 0, 0);
    acc = __builtin_amdgcn_mfma_f32_32x32x16_bf16(kf2, qf2, acc, 0, 0, 0);
    acc = __builtin_amdgcn_mfma_f32_32x32x16_bf16(kf3, qf3, acc, 0, 0, 0);

    const float c = 0.125f * 1.44269504f;
#pragma unroll
    for (int r = 0; r < 4; ++r) accT[r]      += exp2f(acc[r]      * c + (&lv0.x)[r] - l2g);
#pragma unroll
    for (int r = 0; r < 4; ++r) accT[r + 4]  += exp2f(acc[r + 4]  * c + (&lv1.x)[r] - l2g);
#pragma unroll
    for (int r = 0; r < 4; ++r) accT[r + 8]  += exp2f(acc[r + 8]  * c + (&lv2.x)[r] - l2g);
#pragma unroll
    for (int r = 0; r < 4; ++r) accT[r + 12] += exp2f(acc[r + 12] * c + (&lv3.x)[r] - l2g);
  }

  // wave flush into its private LDS segment (idx always in [0,62])
#pragma unroll
  for (int r = 0; r < 16; ++r) {
    int idx = coff + (r & 3) + ((r >> 2) << 3) - (lane & 31) + 31;
    atomicAdd(&Tst[w][idx], accT[r]);
  }
  __syncthreads();

  // block flush: one global atomic per thread
  {
    int seg = tid >> 6, idx = tid & 63;
    int j = jbs[seg] + idx;
    float v = Tst[seg][idx];
    if (idx < 63 && j >= 0 && v != 0.f)
      atomicAdd(&ws[T_OFF + (hb << 10) + j], v);
  }
}

// ---------------------------------------------------------------------------
// Kernel 3: out[b,j,h] = (T[j-1]+T[j]+T[j+1]) / cnt[j]
// ---------------------------------------------------------------------------
__global__ __launch_bounds__(256) void out_kernel(const float* __restrict__ ws,
                                                  float* __restrict__ out)
{
  int o = blockIdx.x * 256 + threadIdx.x;
  if (o >= B * L * H) return;
  int h = o & 7;
  int j = (o >> 3) & 1023;
  int b = o >> 13;
  const float* T = ws + T_OFF + ((h * B + b) << 10);
  float s = T[j];
  float cnt = 3.f;
  if (j > 0) s += T[j - 1];
  if (j < 1023) s += T[j + 1];
  if (j == 0 || j == 1023) cnt = 2.f;
  out[o] = s / cnt;
}

extern "C" void kernel_launch(void* const* d_in, const int* in_sizes, int n_in,
                              void* d_out, int out_size, void* d_ws, size_t ws_size,
                              hipStream_t stream)
{
  const float* x  = (const float*)d_in[0];
  const float* Wq = (const float*)d_in[1];
  const float* bq = (const float*)d_in[2];
  const float* Wk = (const float*)d_in[3];
  const float* bk = (const float*)d_in[4];
  const float* Wv = (const float*)d_in[5];
  const float* pe = (const float*)d_in[6];
  float* ws = (float*)d_ws;
  float* out = (float*)d_out;

  // zero T and gs (adjacent regions) every launch
  (void)hipMemsetAsync(ws + T_OFF, 0, 2 * H * B * L * sizeof(float), stream);
  qkv_kernel<<<dim3((B * L) / 8), dim3(256), 0, stream>>>(x, Wq, bq, Wk, bk, Wv, pe, ws);
  gsum_kernel<<<dim3(2048), dim3(256), 0, stream>>>(ws);
  diag_kernel<<<dim3(1152), dim3(256), 0, stream>>>(ws);
  out_kernel<<<dim3((B * L * H + 255) / 256), dim3(256), 0, stream>>>(ws, out);
}

// Round 8
// 95.783 us; speedup vs baseline: 1.8932x; 1.1844x over previous
//
#include <hip/hip_runtime.h>
#include <hip/hip_bf16.h>
#include <math.h>

#define B 4
#define L 1024
#define D 256
#define H 8
#define HD 64

// workspace layout (float offsets)
#define KB_OFF  (H*B*L*HD/2)           // Q bf16 occupies [0, KB_OFF) floats
#define VR_OFF  (H*B*L*HD)             // K bf16 occupies [KB_OFF, VR_OFF)
#define T_OFF   (VR_OFF + H*B*L)       // diagonal sums (zeroed each launch)
#define GS_OFF  (T_OFF + H*B*L)        // softmax denominators (zeroed each launch)
#define XP_OFF  (GS_OFF + H*B*L)       // xpe bf16 [4096][256]
#define WT_OFF  (XP_OFF + B*L*D/2)     // WT bf16 [1024][256]
// total floats: WT_OFF + 1024*256/2 = 2850816 (~11.4 MB)

typedef short short8 __attribute__((ext_vector_type(8)));
typedef float f32x16 __attribute__((ext_vector_type(16)));

__device__ __forceinline__ unsigned short f2bf(float f) {
  __hip_bfloat16 h = __float2bfloat16(f);
  return *reinterpret_cast<unsigned short*>(&h);
}

// ---------------------------------------------------------------------------
// prep_w: WT[c][d] = (c<512 ? Wq : Wk)[d][c&511], bf16. Grid 32 x 256.
// LDS transpose, +1 pad both phases conflict-free.
// ---------------------------------------------------------------------------
__global__ __launch_bounds__(256) void prep_w_kernel(
    const float* __restrict__ Wq, const float* __restrict__ Wk,
    float* __restrict__ ws)
{
  __shared__ float lds[32][257];
  const int tid = threadIdx.x;
  const int c0 = blockIdx.x * 32;
  const float* W = (c0 < 512) ? Wq : Wk;
  const int cc = c0 & 511;
  const int c = tid & 31, dd = tid >> 5;
  for (int d0 = 0; d0 < 256; d0 += 8)
    lds[c][d0 + dd] = W[(d0 + dd) * 512 + cc + c];
  __syncthreads();
  __hip_bfloat16* WT = (__hip_bfloat16*)(ws + WT_OFF);
  for (int cl = 0; cl < 32; ++cl)
    WT[(c0 + cl) * 256 + tid] = __float2bfloat16(lds[cl][tid]);
}

// ---------------------------------------------------------------------------
// prep_x: XP[gr][d] = bf16(x + pe);  lvr[hb][k] = log2(sigmoid(x@Wv)) reversed.
// Grid 512 x 256 (8 rows/block).
// ---------------------------------------------------------------------------
__global__ __launch_bounds__(256) void prep_x_kernel(
    const float* __restrict__ x, const float* __restrict__ Wv,
    const float* __restrict__ pe, float* __restrict__ ws)
{
  __shared__ float xs[8][257];
  const int tid = threadIdx.x;
  const int r0 = blockIdx.x * 8;
  __hip_bfloat16* XP = (__hip_bfloat16*)(ws + XP_OFF);
  for (int idx = tid; idx < 2048; idx += 256) {
    int rr = idx >> 8, c = idx & 255;
    int gr = r0 + rr, l = gr & 1023;
    float xv = x[gr * 256 + c];
    xs[rr][c] = xv;
    XP[gr * 256 + c] = __float2bfloat16(xv + pe[l * 256 + c]);
  }
  __syncthreads();
  if (tid < 64) {
    int rr = tid >> 3, h = tid & 7;
    float acc = 0.f;
    for (int d = 0; d < 256; ++d) acc += xs[rr][d] * Wv[d * 8 + h];
    float v = 1.f / (1.f + __expf(-acc));
    int gr = r0 + rr;
    int b = gr >> 10, l = gr & 1023;
    ws[VR_OFF + (h * 4 + b) * 1024 + (1023 - l)] = __log2f(v);
  }
}

// ---------------------------------------------------------------------------
// qkgemm: Q|K = bf16(XP @ [Wq|Wk] + bias) via MFMA, written to [hb][l][64].
// 2048 waves: wave = (l-tile 0..127) x (col-pair 0..15). Swapped operands:
// mfma(A=WT rows(outcols), B=XP rows(l)); C col = l (lane&31),
// C row m = (r&3)+8*(r>>2)+4*(lane>>5) = outcol offset. Two chains share B.
// ---------------------------------------------------------------------------
__global__ __launch_bounds__(256) void qkgemm_kernel(float* __restrict__ ws,
    const float* __restrict__ bq, const float* __restrict__ bk)
{
  const int tid = threadIdx.x;
  const int w = tid >> 6, lane = tid & 63;
  const int wid = blockIdx.x * 4 + w;
  const int lt = wid & 127;
  const int cp = wid >> 7;           // 0..15 (0..7 -> Q, 8..15 -> K)

  const __hip_bfloat16* XP = (const __hip_bfloat16*)(ws + XP_OFF);
  const __hip_bfloat16* WT = (const __hip_bfloat16*)(ws + WT_OFF);

  const int ln = (lt << 5) + (lane & 31);       // global row = b*1024 + l
  const int dlo = (lane >> 5) << 3;
  const int ca = (cp << 6) + (lane & 31);       // chain-a outcol row in WT
  const __hip_bfloat16* xr = XP + ln * 256 + dlo;
  const __hip_bfloat16* ar = WT + ca * 256 + dlo;
  const __hip_bfloat16* br = ar + (32 * 256);

  f32x16 acca = {0.f,0.f,0.f,0.f,0.f,0.f,0.f,0.f,0.f,0.f,0.f,0.f,0.f,0.f,0.f,0.f};
  f32x16 accb = {0.f,0.f,0.f,0.f,0.f,0.f,0.f,0.f,0.f,0.f,0.f,0.f,0.f,0.f,0.f,0.f};
#pragma unroll
  for (int k = 0; k < 16; ++k) {
    short8 bf  = *(const short8*)(xr + k * 16);
    short8 afa = *(const short8*)(ar + k * 16);
    short8 afb = *(const short8*)(br + k * 16);
    acca = __builtin_amdgcn_mfma_f32_32x32x16_bf16(afa, bf, acca, 0, 0, 0);
    accb = __builtin_amdgcn_mfma_f32_32x32x16_bf16(afb, bf, accb, 0, 0, 0);
  }

  const int b = ln >> 10, l = ln & 1023;
  const int hq = cp & 7;                        // head
  const int hi4 = (lane >> 5) << 2;
  const float* bias = (cp < 8) ? bq : bk;
  const int cbase = hq << 6;
  __hip_bfloat16* base = (__hip_bfloat16*)ws + ((cp < 8) ? 0 : (size_t)KB_OFF * 2);
  __hip_bfloat16* dst = base + ((((size_t)(hq * 4 + b) << 10) + l) << 6);

#pragma unroll
  for (int q = 0; q < 4; ++q) {
    int hd0 = (q << 3) + hi4;                   // chain a: hd in [0,32)
    float4 bv = *(const float4*)(bias + cbase + hd0);
    ushort4 pk;
    pk.x = f2bf(acca[4 * q + 0] + bv.x);
    pk.y = f2bf(acca[4 * q + 1] + bv.y);
    pk.z = f2bf(acca[4 * q + 2] + bv.z);
    pk.w = f2bf(acca[4 * q + 3] + bv.w);
    *(ushort4*)(dst + hd0) = pk;

    int hd1 = hd0 + 32;                         // chain b: hd in [32,64)
    float4 bw = *(const float4*)(bias + cbase + hd1);
    ushort4 pk2;
    pk2.x = f2bf(accb[4 * q + 0] + bw.x);
    pk2.y = f2bf(accb[4 * q + 1] + bw.y);
    pk2.z = f2bf(accb[4 * q + 2] + bw.z);
    pk2.w = f2bf(accb[4 * q + 3] + bw.w);
    *(ushort4*)(dst + hd1) = pk2;
  }
}

// ---------------------------------------------------------------------------
// Kernel 2a: gs[hb][q] += sum over half the k range of exp(S(q,k)/8).
// Grid 2048 = (khalf 2) x (qt 32) x (hb 32); hb = i&31 -> XCD-pinned.
// ---------------------------------------------------------------------------
__global__ __launch_bounds__(256) void gsum_kernel(float* __restrict__ ws)
{
  __shared__ float smerge[4][32];
  const int tid = threadIdx.x;
  const int w = tid >> 6, lane = tid & 63;
  const int i = blockIdx.x;
  const int hb = i & 31;
  const int qt = (i >> 5) & 31;
  const int khalf = i >> 10;

  const __hip_bfloat16* Qb = (const __hip_bfloat16*)ws + ((size_t)hb << 16);
  const __hip_bfloat16* Kb = (const __hip_bfloat16*)(ws + KB_OFF) + ((size_t)hb << 16);

  const int q0 = qt << 5;
  const int qrow = q0 + (lane & 31);
  const int dlo = (lane >> 5) << 3;

  const __hip_bfloat16* qr = Qb + (qrow << 6) + dlo;
  short8 qf0 = *(const short8*)(qr);
  short8 qf1 = *(const short8*)(qr + 16);
  short8 qf2 = *(const short8*)(qr + 32);
  short8 qf3 = *(const short8*)(qr + 48);

  float s_part = 0.f;
#pragma unroll
  for (int t = 0; t < 2; ++t) {
    const int kta = (khalf << 4) + (t << 3) + w;
    const int ktb = kta + 4;
    const __hip_bfloat16* kra = Kb + (((kta << 5) + (lane & 31)) << 6) + dlo;
    const __hip_bfloat16* krb = Kb + (((ktb << 5) + (lane & 31)) << 6) + dlo;
    short8 ka0 = *(const short8*)(kra);
    short8 ka1 = *(const short8*)(kra + 16);
    short8 ka2 = *(const short8*)(kra + 32);
    short8 ka3 = *(const short8*)(kra + 48);
    short8 kb0 = *(const short8*)(krb);
    short8 kb1 = *(const short8*)(krb + 16);
    short8 kb2 = *(const short8*)(krb + 32);
    short8 kb3 = *(const short8*)(krb + 48);
    f32x16 acca = {0.f,0.f,0.f,0.f,0.f,0.f,0.f,0.f,0.f,0.f,0.f,0.f,0.f,0.f,0.f,0.f};
    f32x16 accb = {0.f,0.f,0.f,0.f,0.f,0.f,0.f,0.f,0.f,0.f,0.f,0.f,0.f,0.f,0.f,0.f};
    acca = __builtin_amdgcn_mfma_f32_32x32x16_bf16(ka0, qf0, acca, 0, 0, 0);
    accb = __builtin_amdgcn_mfma_f32_32x32x16_bf16(kb0, qf0, accb, 0, 0, 0);
    acca = __builtin_amdgcn_mfma_f32_32x32x16_bf16(ka1, qf1, acca, 0, 0, 0);
    accb = __builtin_amdgcn_mfma_f32_32x32x16_bf16(kb1, qf1, accb, 0, 0, 0);
    acca = __builtin_amdgcn_mfma_f32_32x32x16_bf16(ka2, qf2, acca, 0, 0, 0);
    accb = __builtin_amdgcn_mfma_f32_32x32x16_bf16(kb2, qf2, accb, 0, 0, 0);
    acca = __builtin_amdgcn_mfma_f32_32x32x16_bf16(ka3, qf3, acca, 0, 0, 0);
    accb = __builtin_amdgcn_mfma_f32_32x32x16_bf16(kb3, qf3, accb, 0, 0, 0);
#pragma unroll
    for (int r = 0; r < 16; ++r) s_part += __expf(acca[r] * 0.125f);
#pragma unroll
    for (int r = 0; r < 16; ++r) s_part += __expf(accb[r] * 0.125f);
  }
  s_part += __shfl_xor(s_part, 32);
  if (lane < 32) smerge[w][lane] = s_part;
  __syncthreads();
  if (tid < 32) {
    float s = smerge[0][tid] + smerge[1][tid] + smerge[2][tid] + smerge[3][tid];
    atomicAdd(&ws[GS_OFF + (hb << 10) + q0 + tid], s);
  }
}

// ---------------------------------------------------------------------------
// Kernel 2b: diagonal sweep; register accum -> per-wave LDS -> one global
// atomic per thread. Grid 1152 = (cgroup 36) x (hb 32).
// ---------------------------------------------------------------------------
__global__ __launch_bounds__(256) void diag_kernel(float* __restrict__ ws)
{
  __shared__ float Tst[4][64];
  __shared__ int jbs[4];
  const int tid = threadIdx.x;
  const int w = tid >> 6, lane = tid & 63;
  const int i = blockIdx.x;
  const int hb = i & 31;
  const int cg = i >> 5;
  const int chunk = cg * 4 + w;

  int dt = 0, cum = 0;
  for (;;) {
    int n = (32 - dt + 3) >> 2;
    if (chunk < cum + n) break;
    cum += n; ++dt;
  }
  const int qt0 = (chunk - cum) << 2;
  const int qtmax = 31 - dt;

  (&Tst[0][0])[tid] = 0.f;
  if (lane == 0) jbs[w] = (dt << 5) - 31;
  __syncthreads();

  const __hip_bfloat16* Qb = (const __hip_bfloat16*)ws + ((size_t)hb << 16);
  const __hip_bfloat16* Kb = (const __hip_bfloat16*)(ws + KB_OFF) + ((size_t)hb << 16);
  const float* __restrict__ gs = ws + GS_OFF + (hb << 10);
  const float* __restrict__ lvr = ws + VR_OFF + (hb << 10);

  const int dlo = (lane >> 5) << 3;
  const int coff = (lane >> 5) << 2;

  float accT[16];
#pragma unroll
  for (int r = 0; r < 16; ++r) accT[r] = 0.f;

#pragma unroll 2
  for (int u = 0; u < 4; ++u) {
    const int qt = qt0 + u;
    if (qt > qtmax) break;
    const int kt = qt + dt;
    const int qrow = (qt << 5) + (lane & 31);
    const __hip_bfloat16* qr = Qb + (qrow << 6) + dlo;
    const __hip_bfloat16* kr = Kb + (((kt << 5) + (lane & 31)) << 6) + dlo;
    short8 qf0 = *(const short8*)(qr);
    short8 qf1 = *(const short8*)(qr + 16);
    short8 qf2 = *(const short8*)(qr + 32);
    short8 qf3 = *(const short8*)(qr + 48);
    short8 kf0 = *(const short8*)(kr);
    short8 kf1 = *(const short8*)(kr + 16);
    short8 kf2 = *(const short8*)(kr + 32);
    short8 kf3 = *(const short8*)(kr + 48);
    const float* lb = lvr + (kt << 5) + coff;
    float4 lv0 = *(const float4*)(lb);
    float4 lv1 = *(const float4*)(lb + 8);
    float4 lv2 = *(const float4*)(lb + 16);
    float4 lv3 = *(const float4*)(lb + 24);
    float l2g = __log2f(gs[qrow]);

    f32x16 acc = {0.f,0.f,0.f,0.f,0.f,0.f,0.f,0.f,0.f,0.f,0.f,0.f,0.f,0.f,0.f,0.f};
    acc = __builtin_amdgcn_mfma_f32_32x32x16_bf16(kf0, qf0, acc, 0, 0, 0);
    acc = __builtin_amdgcn_mfma_f32_32x32x16_bf16(kf1, qf1, acc, 0, 0, 0);
    acc = __builtin_amdgcn_mfma_f32_32x32x16_bf16(kf2, qf2, acc, 0, 0, 0);
    acc = __builtin_amdgcn_mfma_f32_32x32x16_bf16(kf3, qf3, acc, 0, 0, 0);

    const float c = 0.125f * 1.44269504f;
#pragma unroll
    for (int r = 0; r < 4; ++r) accT[r]      += exp2f(acc[r]      * c + (&lv0.x)[r] - l2g);
#pragma unroll
    for (int r = 0; r < 4; ++r) accT[r + 4]  += exp2f(acc[r + 4]  * c + (&lv1.x)[r] - l2g);
#pragma unroll
    for (int r = 0; r < 4; ++r) accT[r + 8]  += exp2f(acc[r + 8]  * c + (&lv2.x)[r] - l2g);
#pragma unroll
    for (int r = 0; r < 4; ++r) accT[r + 12] += exp2f(acc[r + 12] * c + (&lv3.x)[r] - l2g);
  }

#pragma unroll
  for (int r = 0; r < 16; ++r) {
    int idx = coff + (r & 3) + ((r >> 2) << 3) - (lane & 31) + 31;
    atomicAdd(&Tst[w][idx], accT[r]);
  }
  __syncthreads();

  {
    int seg = tid >> 6, idx = tid & 63;
    int j = jbs[seg] + idx;
    float v = Tst[seg][idx];
    if (idx < 63 && j >= 0 && v != 0.f)
      atomicAdd(&ws[T_OFF + (hb << 10) + j], v);
  }
}

// ---------------------------------------------------------------------------
// Kernel 3: out[b,j,h] = (T[j-1]+T[j]+T[j+1]) / cnt[j]
// ---------------------------------------------------------------------------
__global__ __launch_bounds__(256) void out_kernel(const float* __restrict__ ws,
                                                  float* __restrict__ out)
{
  int o = blockIdx.x * 256 + threadIdx.x;
  if (o >= B * L * H) return;
  int h = o & 7;
  int j = (o >> 3) & 1023;
  int b = o >> 13;
  const float* T = ws + T_OFF + ((h * B + b) << 10);
  float s = T[j];
  float cnt = 3.f;
  if (j > 0) s += T[j - 1];
  if (j < 1023) s += T[j + 1];
  if (j == 0 || j == 1023) cnt = 2.f;
  out[o] = s / cnt;
}

extern "C" void kernel_launch(void* const* d_in, const int* in_sizes, int n_in,
                              void* d_out, int out_size, void* d_ws, size_t ws_size,
                              hipStream_t stream)
{
  const float* x  = (const float*)d_in[0];
  const float* Wq = (const float*)d_in[1];
  const float* bq = (const float*)d_in[2];
  const float* Wk = (const float*)d_in[3];
  const float* bk = (const float*)d_in[4];
  const float* Wv = (const float*)d_in[5];
  const float* pe = (const float*)d_in[6];
  float* ws = (float*)d_ws;
  float* out = (float*)d_out;

  (void)hipMemsetAsync(ws + T_OFF, 0, 2 * H * B * L * sizeof(float), stream);
  prep_w_kernel<<<dim3(32), dim3(256), 0, stream>>>(Wq, Wk, ws);
  prep_x_kernel<<<dim3(512), dim3(256), 0, stream>>>(x, Wv, pe, ws);
  qkgemm_kernel<<<dim3(512), dim3(256), 0, stream>>>(ws, bq, bk);
  gsum_kernel<<<dim3(2048), dim3(256), 0, stream>>>(ws);
  diag_kernel<<<dim3(1152), dim3(256), 0, stream>>>(ws);
  out_kernel<<<dim3((B * L * H + 255) / 256), dim3(256), 0, stream>>>(ws, out);
}